// Round 6
// baseline (324.159 us; speedup 1.0000x reference)
//
#include <hip/hip_runtime.h>
#include <hip/hip_bf16.h>

// Problem: B=16, T=512, E=256, A=8. Inputs f32 (bf16-rounded values),
// mask int32. OUTPUTS ARE F32 (reference returns float32; harness allocates
// d_out in the reference's output dtype):
//   d_out (f32): [ output 16*512*256 | attn 128*512*512 ]
// Math:
//   score[b,a,t,s] = atr[b,a]^2/16 * <sent_t, sent_s> ; mask outer==0 -> 0
//   attn = row softmax (global-max shift is row-invariant)
//   attn_out = attn @ (atr*sent)  (B*A,T,E) -> FLAT reshape (B,T,2048):
//     t' = a*64 + (t>>3),  k = (t&7)*256 + e
//   out = X @ W^T + bias

#define Bt 16
#define Tt 512
#define Et 256
#define At 8

typedef __attribute__((ext_vector_type(8))) short short8;   // 8 x bf16
typedef __attribute__((ext_vector_type(4))) float floatx4;

static __device__ __forceinline__ unsigned short f2bf(float x) {
    union { float f; unsigned u; } v; v.f = x;
    unsigned r = v.u + 0x7fffu + ((v.u >> 16) & 1u);  // RNE
    return (unsigned short)(r >> 16);
}

static __device__ __forceinline__ floatx4 mfma16(short8 a, short8 b, floatx4 c) {
    return __builtin_amdgcn_mfma_f32_16x16x32_bf16(a, b, c, 0, 0, 0);
}

// pack 8 consecutive f32 -> short8 of bf16 (RNE)
static __device__ __forceinline__ short8 pack8(const float* __restrict__ p) {
    float4 lo = *(const float4*)p;
    float4 hi = *(const float4*)(p + 4);
    union { short8 s; unsigned short e[8]; } u;
    u.e[0] = f2bf(lo.x); u.e[1] = f2bf(lo.y); u.e[2] = f2bf(lo.z); u.e[3] = f2bf(lo.w);
    u.e[4] = f2bf(hi.x); u.e[5] = f2bf(hi.y); u.e[6] = f2bf(hi.z); u.e[7] = f2bf(hi.w);
    return u.s;
}

// ---- prep: bf16 copy of sent + bf16 transpose sentT[b][e][s] -------------
__global__ __launch_bounds__(256) void k_prep_sent(const float* __restrict__ sent,
                                                   unsigned short* __restrict__ sentbf,
                                                   unsigned short* __restrict__ sentT) {
    int bb = blockIdx.z;
    int s0 = blockIdx.x * 32;
    int e0 = blockIdx.y * 32;
    __shared__ float tile[32][33];
    int c  = threadIdx.x & 31;
    int r4 = threadIdx.x >> 5;
    for (int i = 0; i < 4; ++i) {
        int r = r4 + 8 * i;
        int gi = (bb * Tt + s0 + r) * Et + e0 + c;
        float v = sent[gi];
        sentbf[gi] = f2bf(v);
        tile[r][c] = v;
    }
    __syncthreads();
    for (int i = 0; i < 4; ++i) {
        int r = r4 + 8 * i;     // e offset in tile
        sentT[(bb * Et + e0 + r) * Tt + s0 + c] = f2bf(tile[c][r]);
    }
}

__global__ __launch_bounds__(256) void k_prep_w(const float* __restrict__ W,
                                                unsigned short* __restrict__ Wbf) {
    int i = blockIdx.x * 256 + threadIdx.x;   // 524288 total
    Wbf[i] = f2bf(W[i]);
}

// ---- K1: Gram via MFMA (shared over a), masked softmax, write attn (f32) -
__global__ __launch_bounds__(256) void k_attn(const unsigned short* __restrict__ sent,
                                              const int* __restrict__ mask,
                                              const float* __restrict__ atr,
                                              float* __restrict__ attnf) {
    int bb = blockIdx.y;
    int t0 = blockIdx.x * 16;
    __shared__ float S[16][516];
    __shared__ float msk[512];
    __shared__ int   mrow[16];
    int tid = threadIdx.x;
    for (int i = tid; i < 512; i += 256) msk[i] = (mask[bb * Tt + i] != 0) ? 1.0f : 0.0f;
    if (tid < 16) mrow[tid] = (mask[bb * Tt + t0 + tid] != 0);

    int wave = tid >> 6, lane = tid & 63, quad = lane >> 4, l16 = lane & 15;

    const unsigned short* Abase = sent + (bb * Tt + t0 + l16) * Et + quad * 8;
    short8 af[8];
#pragma unroll
    for (int kk = 0; kk < 8; ++kk) af[kk] = *(const short8*)(Abase + kk * 32);

#pragma unroll
    for (int i = 0; i < 8; ++i) {
        int nt = wave * 8 + i;      // s-tile 0..31
        const unsigned short* Bbase = sent + (bb * Tt + nt * 16 + l16) * Et + quad * 8;
        floatx4 c = {0.f, 0.f, 0.f, 0.f};
#pragma unroll
        for (int kk = 0; kk < 8; ++kk) {
            short8 bf = *(const short8*)(Bbase + kk * 32);
            c = mfma16(af[kk], bf, c);
        }
#pragma unroll
        for (int r = 0; r < 4; ++r) S[quad * 4 + r][nt * 16 + l16] = c[r];
    }
    __syncthreads();

    int row = tid >> 4, cl = tid & 15;
    int mt = mrow[row];
    float sc[32];
    for (int a = 0; a < At; ++a) {
        float av = atr[bb * At + a];
        float coef = av * av * (1.0f / 16.0f);
        float mx = -1e30f;
#pragma unroll
        for (int j = 0; j < 32; ++j) {
            int cidx = cl + j * 16;
            float v = (mt && msk[cidx] > 0.5f) ? coef * S[row][cidx] : 0.0f;
            sc[j] = v;
            mx = fmaxf(mx, v);
        }
#pragma unroll
        for (int off = 8; off >= 1; off >>= 1) mx = fmaxf(mx, __shfl_xor(mx, off, 64));
        float sum = 0.f;
#pragma unroll
        for (int j = 0; j < 32; ++j) { float p = __expf(sc[j] - mx); sc[j] = p; sum += p; }
#pragma unroll
        for (int off = 8; off >= 1; off >>= 1) sum += __shfl_xor(sum, off, 64);
        float inv = 1.0f / sum;
        float* orow = attnf + ((size_t)(bb * At + a) * Tt + (t0 + row)) * Tt;
#pragma unroll
        for (int j = 0; j < 32; ++j) orow[cl + j * 16] = sc[j] * inv;
    }
}

// ---- K2 fused: attn_out slab -> LDS (flat-reshape layout) -> @ W^T + b ---
// Block (tt, a, bb): out rows t' = a*64 + tt*16 + tp, tp in [0,16);
// needs attn_out[ba] rows t in [tt*128, tt*128+128).
// LDS X[tp][k]: k = (t&7)*256 + e. Octet-XOR swizzle:
//   elem k of row tp at ((k>>3)^tp)*8 + (k&7).
__global__ __launch_bounds__(256) void k_fused(const float* __restrict__ attnf,
                                               const unsigned short* __restrict__ sentT,
                                               const unsigned short* __restrict__ W,
                                               const float* __restrict__ atr,
                                               const float* __restrict__ bias,
                                               float* __restrict__ out) {
    int tt = blockIdx.x;            // 0..3
    int a  = blockIdx.y;            // 0..7
    int bb = blockIdx.z;            // 0..15
    int tid = threadIdx.x, wave = tid >> 6, lane = tid & 63, quad = lane >> 4, l16 = lane & 15;
    float av = atr[bb * At + a];

    __shared__ unsigned short X[16 * 2048];   // 64 KB

    // ---- stage 1: attn_out rows tt*128..+128, e-cols split by wave
    const float* Abase = attnf + (((size_t)(bb * At + a) * Tt) + tt * 128 + l16) * Tt + quad * 8;
    const unsigned short* Bbase = sentT + ((size_t)bb * Et + wave * 64 + l16) * Tt + quad * 8;

    for (int mh = 0; mh < 2; ++mh) {
        floatx4 acc[4][4];
#pragma unroll
        for (int mi = 0; mi < 4; ++mi)
#pragma unroll
            for (int i = 0; i < 4; ++i) acc[mi][i] = (floatx4){0.f, 0.f, 0.f, 0.f};

        for (int k0 = 0; k0 < Tt; k0 += 32) {
            short8 bfr[4];
#pragma unroll
            for (int i = 0; i < 4; ++i) bfr[i] = *(const short8*)(Bbase + i * 16 * Tt + k0);
#pragma unroll
            for (int mi = 0; mi < 4; ++mi) {
                short8 afr = pack8(Abase + (mh * 4 + mi) * 16 * Tt + k0);
#pragma unroll
                for (int i = 0; i < 4; ++i) acc[mi][i] = mfma16(afr, bfr[i], acc[mi][i]);
            }
        }
#pragma unroll
        for (int mi = 0; mi < 4; ++mi) {
#pragma unroll
            for (int i = 0; i < 4; ++i) {
                int e = (wave * 4 + i) * 16 + l16;
#pragma unroll
                for (int r = 0; r < 4; ++r) {
                    int tloc = (mh * 4 + mi) * 16 + quad * 4 + r;   // 0..127
                    int tp = tloc >> 3, j = tloc & 7;
                    int k = j * 256 + e;
                    X[tp * 2048 + (((k >> 3) ^ tp) << 3) + (k & 7)] = f2bf(av * acc[mi][i][r]);
                }
            }
        }
    }
    __syncthreads();

    // ---- stage 2: out[16 x 256] = X @ W^T + bias, n-cols split by wave
    floatx4 oacc[4];
#pragma unroll
    for (int i = 0; i < 4; ++i) oacc[i] = (floatx4){0.f, 0.f, 0.f, 0.f};

    const int KK = At * Et;  // 2048
    for (int k0 = 0; k0 < KK; k0 += 32) {
        int oc = (k0 >> 3) + quad;
        short8 afr = *(const short8*)(&X[l16 * 2048 + ((oc ^ l16) << 3)]);
#pragma unroll
        for (int i = 0; i < 4; ++i) {
            int nrow = (wave * 4 + i) * 16 + l16;
            short8 bf = *(const short8*)(W + (size_t)nrow * KK + k0 + quad * 8);
            oacc[i] = mfma16(afr, bf, oacc[i]);
        }
    }
#pragma unroll
    for (int i = 0; i < 4; ++i) {
        int n = (wave * 4 + i) * 16 + l16;
        float bv = bias[n];
#pragma unroll
        for (int r = 0; r < 4; ++r) {
            int tp = a * 64 + tt * 16 + quad * 4 + r;
            out[((size_t)bb * Tt + tp) * Et + n] = oacc[i][r] + bv;
        }
    }
}

extern "C" void kernel_launch(void* const* d_in, const int* in_sizes, int n_in,
                              void* d_out, int out_size, void* d_ws, size_t ws_size,
                              hipStream_t stream) {
    const float* sent = (const float*)d_in[0];   // f32 (B,T,E)
    const int*   mask = (const int*)d_in[1];     // int32 (B,T)
    const float* atr  = (const float*)d_in[2];   // f32 (B,A)
    const float* W    = (const float*)d_in[3];   // f32 (E, A*E)
    const float* bias = (const float*)d_in[4];   // f32 (E)

    float* out0  = (float*)d_out;                     // 2,097,152 f32
    float* attnf = out0 + (size_t)Bt * Tt * Et;       // 33,554,432 f32

    char* ws = (char*)d_ws;
    unsigned short* sentbf = (unsigned short*)(ws);             // 4 MB
    unsigned short* sentT  = (unsigned short*)(ws + 4194304);   // 4 MB
    unsigned short* Wbf    = (unsigned short*)(ws + 8388608);   // 1 MB
    // total ws use: 9.4 MB (<= 43 MB proven safe in R2)

    hipLaunchKernelGGL(k_prep_sent, dim3(Tt / 32, Et / 32, Bt), dim3(256), 0, stream,
                       sent, sentbf, sentT);
    hipLaunchKernelGGL(k_prep_w, dim3((Et * At * Et) / 256), dim3(256), 0, stream, W, Wbf);
    hipLaunchKernelGGL(k_attn, dim3(Tt / 16, Bt), dim3(256), 0, stream,
                       sentbf, mask, atr, attnf);
    hipLaunchKernelGGL(k_fused, dim3(4, At, Bt), dim3(256), 0, stream,
                       attnf, sentT, Wbf, atr, bias, out0);
}

// Round 7
// 314.295 us; speedup vs baseline: 1.0314x; 1.0314x over previous
//
#include <hip/hip_runtime.h>
#include <hip/hip_bf16.h>

// B=16, T=512, E=256, A=8. Inputs f32 (+int32 mask), outputs f32:
//   d_out: [ output 16*512*256 | attn 128*512*512 ]  (both f32)
// score[b,a,t,s] = atr^2/16 * <sent_t,sent_s>, mask-outer==0 -> 0,
// row softmax; attn_out = attn @ (atr*sent) flat-reshaped (B,T,2048); @W^T+b.

#define Bt 16
#define Tt 512
#define Et 256
#define At 8

typedef __attribute__((ext_vector_type(8))) short short8;   // 8 x bf16
typedef __attribute__((ext_vector_type(4))) float floatx4;

static __device__ __forceinline__ unsigned short f2bf(float x) {
    union { float f; unsigned u; } v; v.f = x;
    unsigned r = v.u + 0x7fffu + ((v.u >> 16) & 1u);  // RNE
    return (unsigned short)(r >> 16);
}

static __device__ __forceinline__ floatx4 mfma16(short8 a, short8 b, floatx4 c) {
    return __builtin_amdgcn_mfma_f32_16x16x32_bf16(a, b, c, 0, 0, 0);
}

// pack 8 consecutive f32 -> 8 bf16 via v_perm (round-to-nearest, ties-away).
// attn values are >=0 and <=1 so the +0x8000 bias cannot overflow.
static __device__ __forceinline__ short8 pack8(const float* __restrict__ p) {
    uint4 lo = *(const uint4*)p;
    uint4 hi = *(const uint4*)(p + 4);
    union { short8 s; unsigned u[4]; } r;
    r.u[0] = __builtin_amdgcn_perm(lo.y + 0x8000u, lo.x + 0x8000u, 0x07060302u);
    r.u[1] = __builtin_amdgcn_perm(lo.w + 0x8000u, lo.z + 0x8000u, 0x07060302u);
    r.u[2] = __builtin_amdgcn_perm(hi.y + 0x8000u, hi.x + 0x8000u, 0x07060302u);
    r.u[3] = __builtin_amdgcn_perm(hi.w + 0x8000u, hi.z + 0x8000u, 0x07060302u);
    return r.s;
}

// ---- prep: bf16 copy of sent + bf16 transpose sentT[b][e][s] -------------
__global__ __launch_bounds__(256) void k_prep_sent(const float* __restrict__ sent,
                                                   unsigned short* __restrict__ sentbf,
                                                   unsigned short* __restrict__ sentT) {
    int bb = blockIdx.z;
    int s0 = blockIdx.x * 32;
    int e0 = blockIdx.y * 32;
    __shared__ float tile[32][33];
    int c  = threadIdx.x & 31;
    int r4 = threadIdx.x >> 5;
    for (int i = 0; i < 4; ++i) {
        int r = r4 + 8 * i;
        int gi = (bb * Tt + s0 + r) * Et + e0 + c;
        float v = sent[gi];
        sentbf[gi] = f2bf(v);
        tile[r][c] = v;
    }
    __syncthreads();
    for (int i = 0; i < 4; ++i) {
        int r = r4 + 8 * i;
        sentT[(bb * Et + e0 + r) * Tt + s0 + c] = f2bf(tile[c][r]);
    }
}

__global__ __launch_bounds__(256) void k_prep_w(const float* __restrict__ W,
                                                unsigned short* __restrict__ Wbf) {
    int i = blockIdx.x * 256 + threadIdx.x;
    Wbf[i] = f2bf(W[i]);
}

// ---- K1: Gram via MFMA (shared over all a), single-pass softmax ----------
__global__ __launch_bounds__(256) void k_attn(const unsigned short* __restrict__ sent,
                                              const int* __restrict__ mask,
                                              const float* __restrict__ atr,
                                              float* __restrict__ attnf) {
    int bb = blockIdx.y;
    int t0 = blockIdx.x * 16;
    __shared__ float S[16][516];
    __shared__ float msk[512];
    __shared__ int   mrow[16];
    int tid = threadIdx.x;
    for (int i = tid; i < 512; i += 256) msk[i] = (mask[bb * Tt + i] != 0) ? 1.0f : 0.0f;
    if (tid < 16) mrow[tid] = (mask[bb * Tt + t0 + tid] != 0);

    int wave = tid >> 6, lane = tid & 63, quad = lane >> 4, l16 = lane & 15;

    const unsigned short* Abase = sent + (bb * Tt + t0 + l16) * Et + quad * 8;
    short8 af[8];
#pragma unroll
    for (int kk = 0; kk < 8; ++kk) af[kk] = *(const short8*)(Abase + kk * 32);

#pragma unroll
    for (int i = 0; i < 8; ++i) {
        int nt = wave * 8 + i;
        const unsigned short* Bbase = sent + (bb * Tt + nt * 16 + l16) * Et + quad * 8;
        floatx4 c = {0.f, 0.f, 0.f, 0.f};
#pragma unroll
        for (int kk = 0; kk < 8; ++kk) {
            short8 bf = *(const short8*)(Bbase + kk * 32);
            c = mfma16(af[kk], bf, c);
        }
#pragma unroll
        for (int r = 0; r < 4; ++r) S[quad * 4 + r][nt * 16 + l16] = c[r];
    }
    __syncthreads();

    // softmax: thread (row=tid>>4, cl=tid&15) owns cols {cl+16j}.
    // w_j = S * maskbit (0 where masked) hoisted to regs ONCE; since
    // coef = atr^2/16 >= 0: rowmax_a = coef * max_j(w_j) -> one reduction.
    int row = tid >> 4, cl = tid & 15;
    float mtf = mrow[row] ? 1.0f : 0.0f;
    float w[32];
    float wmax = -1e30f;
#pragma unroll
    for (int j = 0; j < 32; ++j) {
        int cidx = cl + j * 16;
        float v = S[row][cidx] * msk[cidx] * mtf;
        w[j] = v;
        wmax = fmaxf(wmax, v);
    }
#pragma unroll
    for (int off = 8; off >= 1; off >>= 1) wmax = fmaxf(wmax, __shfl_xor(wmax, off, 64));
    // wmax >= 0 always (masked entries contribute 0)

    for (int a = 0; a < At; ++a) {
        float av = atr[bb * At + a];
        float coef = av * av * (1.0f / 16.0f);
        float mx = coef * wmax;
        float p[32];
        float sum = 0.f;
#pragma unroll
        for (int j = 0; j < 32; ++j) {
            float e = __expf(fmaf(coef, w[j], -mx));
            p[j] = e;
            sum += e;
        }
#pragma unroll
        for (int off = 8; off >= 1; off >>= 1) sum += __shfl_xor(sum, off, 64);
        float inv = 1.0f / sum;
        float* orow = attnf + ((size_t)(bb * At + a) * Tt + (t0 + row)) * Tt;
#pragma unroll
        for (int j = 0; j < 32; ++j) orow[cl + j * 16] = p[j] * inv;
    }
}

// ---- K2 fused (512 thr): attn_out slab -> LDS X (flat layout) -> @W^T+b --
// Block (tt,a,bb). Stage1: wave wv: mh = wv>>2 (row half), nb = wv&3 (e 64).
// LDS X[tp][k], k=(t&7)*256+e, octet-XOR swizzle ((k>>3)^tp)*8 + (k&7).
// Stage2: wave wv handles n-tiles {2wv, 2wv+1}.
__global__ __launch_bounds__(512, 4) void k_fused(const float* __restrict__ attnf,
                                                  const unsigned short* __restrict__ sentT,
                                                  const unsigned short* __restrict__ W,
                                                  const float* __restrict__ atr,
                                                  const float* __restrict__ bias,
                                                  float* __restrict__ out) {
    int tt = blockIdx.x;            // 0..3
    int a  = blockIdx.y;            // 0..7
    int bb = blockIdx.z;            // 0..15
    int tid = threadIdx.x;
    int wv = tid >> 6, lane = tid & 63, quad = lane >> 4, l16 = lane & 15;
    int mh = wv >> 2, nb = wv & 3;
    float av = atr[bb * At + a];

    __shared__ unsigned short X[16 * 2048];   // 64 KB

    // ---- stage 1: attn_out rows [tt*128 + mh*64 .. +64), e-cols nb*64..+64
    const float* Abase = attnf + (((size_t)(bb * At + a) * Tt) + tt * 128 + mh * 64 + l16) * Tt + quad * 8;
    const unsigned short* Bbase = sentT + ((size_t)bb * Et + nb * 64 + l16) * Tt + quad * 8;

    floatx4 acc[4][4];
#pragma unroll
    for (int mi = 0; mi < 4; ++mi)
#pragma unroll
        for (int i = 0; i < 4; ++i) acc[mi][i] = (floatx4){0.f, 0.f, 0.f, 0.f};

    for (int k0 = 0; k0 < Tt; k0 += 32) {
        short8 bfr[4];
#pragma unroll
        for (int i = 0; i < 4; ++i) bfr[i] = *(const short8*)(Bbase + i * 16 * Tt + k0);
#pragma unroll
        for (int mi = 0; mi < 4; ++mi) {
            short8 afr = pack8(Abase + mi * 16 * Tt + k0);
#pragma unroll
            for (int i = 0; i < 4; ++i) acc[mi][i] = mfma16(afr, bfr[i], acc[mi][i]);
        }
    }
#pragma unroll
    for (int mi = 0; mi < 4; ++mi) {
#pragma unroll
        for (int i = 0; i < 4; ++i) {
            int e = (nb * 4 + i) * 16 + l16;
#pragma unroll
            for (int r = 0; r < 4; ++r) {
                int tloc = mh * 64 + mi * 16 + quad * 4 + r;   // 0..127
                int tp = tloc >> 3, j = tloc & 7;
                int k = j * 256 + e;
                X[tp * 2048 + (((k >> 3) ^ tp) << 3) + (k & 7)] = f2bf(av * acc[mi][i][r]);
            }
        }
    }
    __syncthreads();

    // ---- stage 2: out[16 x 256] = X @ W^T + bias; wave wv -> n-tiles 2wv,2wv+1
    floatx4 oacc[2];
    oacc[0] = (floatx4){0.f, 0.f, 0.f, 0.f};
    oacc[1] = (floatx4){0.f, 0.f, 0.f, 0.f};

    const int KK = At * Et;  // 2048
    for (int k0 = 0; k0 < KK; k0 += 32) {
        int oc = (k0 >> 3) + quad;
        short8 afr = *(const short8*)(&X[l16 * 2048 + ((oc ^ l16) << 3)]);
#pragma unroll
        for (int i = 0; i < 2; ++i) {
            int nrow = (wv * 2 + i) * 16 + l16;
            short8 bf = *(const short8*)(W + (size_t)nrow * KK + k0 + quad * 8);
            oacc[i] = mfma16(afr, bf, oacc[i]);
        }
    }
#pragma unroll
    for (int i = 0; i < 2; ++i) {
        int n = (wv * 2 + i) * 16 + l16;
        float bv = bias[n];
#pragma unroll
        for (int r = 0; r < 4; ++r) {
            int tp = a * 64 + tt * 16 + quad * 4 + r;
            out[((size_t)bb * Tt + tp) * Et + n] = oacc[i][r] + bv;
        }
    }
}

extern "C" void kernel_launch(void* const* d_in, const int* in_sizes, int n_in,
                              void* d_out, int out_size, void* d_ws, size_t ws_size,
                              hipStream_t stream) {
    const float* sent = (const float*)d_in[0];   // f32 (B,T,E)
    const int*   mask = (const int*)d_in[1];     // int32 (B,T)
    const float* atr  = (const float*)d_in[2];   // f32 (B,A)
    const float* W    = (const float*)d_in[3];   // f32 (E, A*E)
    const float* bias = (const float*)d_in[4];   // f32 (E)

    float* out0  = (float*)d_out;                     // 2,097,152 f32
    float* attnf = out0 + (size_t)Bt * Tt * Et;       // 33,554,432 f32

    char* ws = (char*)d_ws;
    unsigned short* sentbf = (unsigned short*)(ws);             // 4 MB
    unsigned short* sentT  = (unsigned short*)(ws + 4194304);   // 4 MB
    unsigned short* Wbf    = (unsigned short*)(ws + 8388608);   // 1 MB

    hipLaunchKernelGGL(k_prep_sent, dim3(Tt / 32, Et / 32, Bt), dim3(256), 0, stream,
                       sent, sentbf, sentT);
    hipLaunchKernelGGL(k_prep_w, dim3((Et * At * Et) / 256), dim3(256), 0, stream, W, Wbf);
    hipLaunchKernelGGL(k_attn, dim3(Tt / 16, Bt), dim3(256), 0, stream,
                       sentbf, mask, atr, attnf);
    hipLaunchKernelGGL(k_fused, dim3(4, At, Bt), dim3(512), 0, stream,
                       attnf, sentT, Wbf, atr, bias, out0);
}